// Round 4
// baseline (574.582 us; speedup 1.0000x reference)
//
#include <hip/hip_runtime.h>

#define N_IMG 8
#define K_INS 16
#define CCH   64
#define SPL   4      // HW split per (n,c) -> 2048 blocks, 8 blocks/CU
#define EPSV  1e-5f

// workspace layout (bytes):
//   [0, 262144)        float2 P[N][K][C][SPL]  partial (sum,sumsq) -- fully written each call
//   [262144, 262656)   int    cnt[N][K]        -- zeroed via hipMemsetAsync each call
#define P_OFF   0
#define CNT_OFF 262144

__global__ __launch_bounds__(256) void count_kernel(const int* __restrict__ ids,
                                                    int* __restrict__ cnt, int HW) {
    // grid: (HW/256, N). one id per thread; per-wave ballot histogram.
    const int n = blockIdx.y;
    const int gid = blockIdx.x * 256 + threadIdx.x;
    const int lane = threadIdx.x & 63;
    const int id = ids[(size_t)n * HW + gid];
#pragma unroll
    for (int k = 0; k < K_INS; ++k) {
        unsigned long long m = __ballot(id == k);
        if (lane == 0) atomicAdd(&cnt[n * K_INS + k], __popcll(m));
    }
}

__global__ __launch_bounds__(256) void stats_kernel(const float* __restrict__ x,
                                                    const int* __restrict__ ids,
                                                    float2* __restrict__ P, int HW) {
    // grid: (C, N, SPL). Block owns chunk s of (n,c): HW/SPL elements.
    // Register-resident predicated accumulation (all indices compile-time),
    // then per-wave shfl reduction -> 512B LDS -> one float2 per k to global.
    const int c = blockIdx.x;
    const int n = blockIdx.y;
    const int sb = blockIdx.z;
    const int t = threadIdx.x;
    const int chunk = HW / SPL;  // 16384

    float s[K_INS], q[K_INS];
#pragma unroll
    for (int k = 0; k < K_INS; ++k) { s[k] = 0.f; q[k] = 0.f; }

    const float4* x4 = (const float4*)(x + ((size_t)n * CCH + c) * HW + (size_t)sb * chunk);
    const int4* i4 = (const int4*)(ids + (size_t)n * HW + (size_t)sb * chunk);

    const int iters = chunk / (256 * 4);  // 16
#pragma unroll 4
    for (int j = 0; j < iters; ++j) {
        int idx = j * 256 + t;
        float4 xv = x4[idx];
        int4 iv = i4[idx];
#pragma unroll
        for (int k = 0; k < K_INS; ++k) {
            float m0 = (iv.x == k) ? xv.x : 0.f;
            s[k] += m0;
            q[k] = fmaf(m0, xv.x, q[k]);
            float m1 = (iv.y == k) ? xv.y : 0.f;
            s[k] += m1;
            q[k] = fmaf(m1, xv.y, q[k]);
            float m2 = (iv.z == k) ? xv.z : 0.f;
            s[k] += m2;
            q[k] = fmaf(m2, xv.z, q[k]);
            float m3 = (iv.w == k) ? xv.w : 0.f;
            s[k] += m3;
            q[k] = fmaf(m3, xv.w, q[k]);
        }
    }

    // per-wave tree reduce, tiny LDS for cross-wave
    __shared__ float2 wsum[4][K_INS];
    const int wave = t >> 6, lane = t & 63;
#pragma unroll
    for (int k = 0; k < K_INS; ++k) {
        float a = s[k], b = q[k];
#pragma unroll
        for (int off = 32; off > 0; off >>= 1) {
            a += __shfl_down(a, off);
            b += __shfl_down(b, off);
        }
        if (lane == 0) wsum[wave][k] = make_float2(a, b);
    }
    __syncthreads();
    if (t < K_INS) {
        float2 r = wsum[0][t];
#pragma unroll
        for (int w = 1; w < 4; ++w) {
            r.x += wsum[w][t].x;
            r.y += wsum[w][t].y;
        }
        P[((size_t)(n * K_INS + t) * CCH + c) * SPL + sb] = r;
    }
}

__global__ __launch_bounds__(256) void norm_kernel(const float* __restrict__ x,
                                                   const int* __restrict__ ids,
                                                   const float2* __restrict__ P,
                                                   const int* __restrict__ cnt,
                                                   const float* __restrict__ gamma,
                                                   const float* __restrict__ beta,
                                                   float* __restrict__ out, int HW) {
    // grid: (C, N, SPL). Head: 16 threads fold SPL partials + count -> scale/shift.
    const int c = blockIdx.x;
    const int n = blockIdx.y;
    const int sb = blockIdx.z;
    const int t = threadIdx.x;
    const int chunk = HW / SPL;

    __shared__ float2 ls[K_INS];
    if (t < K_INS) {
        float rs = 0.f, rq = 0.f;
#pragma unroll
        for (int sp = 0; sp < SPL; ++sp) {
            float2 v = P[((size_t)(n * K_INS + t) * CCH + c) * SPL + sp];
            rs += v.x;
            rq += v.y;
        }
        float denom = fmaxf((float)cnt[n * K_INS + t], 1.0f);
        float mean = rs / denom;
        float var = rq / denom - mean * mean;
        float r = rsqrtf(var + EPSV);
        float sc = r * gamma[c];
        float sh = beta[c] - mean * sc;
        ls[t] = make_float2(sc, sh);
    }
    __syncthreads();

    const float4* xp = (const float4*)(x + ((size_t)n * CCH + c) * HW + (size_t)sb * chunk);
    const int4* ip = (const int4*)(ids + (size_t)n * HW + (size_t)sb * chunk);
    float4* op = (float4*)(out + ((size_t)n * CCH + c) * HW + (size_t)sb * chunk);

    const int iters = chunk / (256 * 4);  // 16
#pragma unroll 4
    for (int j = 0; j < iters; ++j) {
        int idx = j * 256 + t;
        float4 xv = xp[idx];
        int4 id = ip[idx];
        float4 o;
        {
            float2 ss = ls[max(id.x, 0)];
            o.x = (id.x >= 0) ? fmaf(xv.x, ss.x, ss.y) : xv.x;
        }
        {
            float2 ss = ls[max(id.y, 0)];
            o.y = (id.y >= 0) ? fmaf(xv.y, ss.x, ss.y) : xv.y;
        }
        {
            float2 ss = ls[max(id.z, 0)];
            o.z = (id.z >= 0) ? fmaf(xv.z, ss.x, ss.y) : xv.z;
        }
        {
            float2 ss = ls[max(id.w, 0)];
            o.w = (id.w >= 0) ? fmaf(xv.w, ss.x, ss.y) : xv.w;
        }
        op[idx] = o;
    }
}

extern "C" void kernel_launch(void* const* d_in, const int* in_sizes, int n_in,
                              void* d_out, int out_size, void* d_ws, size_t ws_size,
                              hipStream_t stream) {
    const float* x = (const float*)d_in[0];
    const int* ids = (const int*)d_in[1];
    const float* gamma = (const float*)d_in[2];
    const float* beta = (const float*)d_in[3];
    float* out = (float*)d_out;

    const int HW = in_sizes[1] / N_IMG;  // 65536

    float2* P = (float2*)((char*)d_ws + P_OFF);
    int* cnt = (int*)((char*)d_ws + CNT_OFF);

    // counts are accumulated with atomics -> must be zeroed every call
    hipMemsetAsync((char*)d_ws + CNT_OFF, 0, N_IMG * K_INS * sizeof(int), stream);

    count_kernel<<<dim3(HW / 256, N_IMG), 256, 0, stream>>>(ids, cnt, HW);
    stats_kernel<<<dim3(CCH, N_IMG, SPL), 256, 0, stream>>>(x, ids, P, HW);
    norm_kernel<<<dim3(CCH, N_IMG, SPL), 256, 0, stream>>>(x, ids, P, cnt, gamma, beta, out, HW);
}

// Round 6
// 153.130 us; speedup vs baseline: 3.7523x; 3.7523x over previous
//
#include <hip/hip_runtime.h>

#define N_IMG 8
#define K_INS 16
#define CCH   64
#define SPL   4      // HW split per (n,c) -> 2048 blocks, 8 blocks/CU, 32 waves/CU
#define EPSV  1e-5f

typedef float vfloat4 __attribute__((ext_vector_type(4)));

// workspace layout (bytes):
//   [0, 262144)        float2 P[N][K][C][SPL]  partial (sum,sumsq) -- fully written each call
//   [262144, 262656)   int    cnt[N][K]        -- zeroed via hipMemsetAsync each call
#define P_OFF   0
#define CNT_OFF 262144

__global__ __launch_bounds__(256) void count_kernel(const int* __restrict__ ids,
                                                    int* __restrict__ cnt, int HW) {
    // grid: (32, N). tile = HW/32 ids; each of 4 waves takes a quarter.
    // Register-accumulated ballot histogram: only 16 atomics per WAVE total
    // (16K atomics on 128 words -- low contention, unlike 131K in round 4).
    const int n = blockIdx.y;
    const int tileSize = HW / 32;
    const int quarter = tileSize / 4;
    const int lane = threadIdx.x & 63;
    const int wave = threadIdx.x >> 6;
    const int wbase = blockIdx.x * tileSize + wave * quarter;
    const int* p = ids + (size_t)n * HW;

    int myc[K_INS];
#pragma unroll
    for (int k = 0; k < K_INS; ++k) myc[k] = 0;

    for (int i = wbase + lane; i < wbase + quarter; i += 64) {
        int id = p[i];
#pragma unroll
        for (int k = 0; k < K_INS; ++k) {
            unsigned long long m = __ballot(id == k);
            if (lane == 0) myc[k] += __popcll(m);
        }
    }
    if (lane == 0) {
#pragma unroll
        for (int k = 0; k < K_INS; ++k) atomicAdd(&cnt[n * K_INS + k], myc[k]);
    }
}

__global__ __launch_bounds__(256) void stats_kernel(const float* __restrict__ x,
                                                    const int* __restrict__ ids,
                                                    float2* __restrict__ P, int HW) {
    // grid: (C, N, SPL). Block owns chunk sb of (n,c): HW/SPL elements.
    // Register-resident predicated accumulation (all indices compile-time),
    // then per-wave shfl reduction -> 512B LDS -> one float2 per k to global.
    const int c = blockIdx.x;
    const int n = blockIdx.y;
    const int sb = blockIdx.z;
    const int t = threadIdx.x;
    const int chunk = HW / SPL;  // 16384

    float s[K_INS], q[K_INS];
#pragma unroll
    for (int k = 0; k < K_INS; ++k) { s[k] = 0.f; q[k] = 0.f; }

    const float4* x4 = (const float4*)(x + ((size_t)n * CCH + c) * HW + (size_t)sb * chunk);
    const int4* i4 = (const int4*)(ids + (size_t)n * HW + (size_t)sb * chunk);

    const int iters = chunk / (256 * 4);  // 16
#pragma unroll 4
    for (int j = 0; j < iters; ++j) {
        int idx = j * 256 + t;
        float4 xv = x4[idx];
        int4 iv = i4[idx];
#pragma unroll
        for (int k = 0; k < K_INS; ++k) {
            float m0 = (iv.x == k) ? xv.x : 0.f;
            s[k] += m0;
            q[k] = fmaf(m0, xv.x, q[k]);
            float m1 = (iv.y == k) ? xv.y : 0.f;
            s[k] += m1;
            q[k] = fmaf(m1, xv.y, q[k]);
            float m2 = (iv.z == k) ? xv.z : 0.f;
            s[k] += m2;
            q[k] = fmaf(m2, xv.z, q[k]);
            float m3 = (iv.w == k) ? xv.w : 0.f;
            s[k] += m3;
            q[k] = fmaf(m3, xv.w, q[k]);
        }
    }

    // per-wave tree reduce, tiny LDS for cross-wave
    __shared__ float2 wsum[4][K_INS];
    const int wave = t >> 6, lane = t & 63;
#pragma unroll
    for (int k = 0; k < K_INS; ++k) {
        float a = s[k], b = q[k];
#pragma unroll
        for (int off = 32; off > 0; off >>= 1) {
            a += __shfl_down(a, off);
            b += __shfl_down(b, off);
        }
        if (lane == 0) wsum[wave][k] = make_float2(a, b);
    }
    __syncthreads();
    if (t < K_INS) {
        float2 r = wsum[0][t];
#pragma unroll
        for (int w = 1; w < 4; ++w) {
            r.x += wsum[w][t].x;
            r.y += wsum[w][t].y;
        }
        P[((size_t)(n * K_INS + t) * CCH + c) * SPL + sb] = r;
    }
}

__global__ __launch_bounds__(256) void norm_kernel(const float* __restrict__ x,
                                                   const int* __restrict__ ids,
                                                   const float2* __restrict__ P,
                                                   const int* __restrict__ cnt,
                                                   const float* __restrict__ gamma,
                                                   const float* __restrict__ beta,
                                                   float* __restrict__ out, int HW) {
    // grid: (C, N, SPL). Head: 16 threads fold SPL partials + count -> scale/shift.
    const int c = blockIdx.x;
    const int n = blockIdx.y;
    const int sb = blockIdx.z;
    const int t = threadIdx.x;
    const int chunk = HW / SPL;

    __shared__ float2 ls[K_INS];
    if (t < K_INS) {
        float rs = 0.f, rq = 0.f;
#pragma unroll
        for (int sp = 0; sp < SPL; ++sp) {
            float2 v = P[((size_t)(n * K_INS + t) * CCH + c) * SPL + sp];
            rs += v.x;
            rq += v.y;
        }
        float denom = fmaxf((float)cnt[n * K_INS + t], 1.0f);
        float mean = rs / denom;
        float var = rq / denom - mean * mean;
        float r = rsqrtf(var + EPSV);
        float sc = r * gamma[c];
        float sh = beta[c] - mean * sc;
        ls[t] = make_float2(sc, sh);
    }
    __syncthreads();

    const float4* xp = (const float4*)(x + ((size_t)n * CCH + c) * HW + (size_t)sb * chunk);
    const int4* ip = (const int4*)(ids + (size_t)n * HW + (size_t)sb * chunk);
    vfloat4* op = (vfloat4*)(out + ((size_t)n * CCH + c) * HW + (size_t)sb * chunk);

    const int iters = chunk / (256 * 4);  // 16
#pragma unroll 4
    for (int j = 0; j < iters; ++j) {
        int idx = j * 256 + t;
        float4 xv = xp[idx];
        int4 id = ip[idx];
        vfloat4 o;
        {
            float2 ss = ls[max(id.x, 0)];
            o.x = (id.x >= 0) ? fmaf(xv.x, ss.x, ss.y) : xv.x;
        }
        {
            float2 ss = ls[max(id.y, 0)];
            o.y = (id.y >= 0) ? fmaf(xv.y, ss.x, ss.y) : xv.y;
        }
        {
            float2 ss = ls[max(id.z, 0)];
            o.z = (id.z >= 0) ? fmaf(xv.z, ss.x, ss.y) : xv.z;
        }
        {
            float2 ss = ls[max(id.w, 0)];
            o.w = (id.w >= 0) ? fmaf(xv.w, ss.x, ss.y) : xv.w;
        }
        // out is never re-read: nontemporal store keeps x resident in L3
        __builtin_nontemporal_store(o, &op[idx]);
    }
}

extern "C" void kernel_launch(void* const* d_in, const int* in_sizes, int n_in,
                              void* d_out, int out_size, void* d_ws, size_t ws_size,
                              hipStream_t stream) {
    const float* x = (const float*)d_in[0];
    const int* ids = (const int*)d_in[1];
    const float* gamma = (const float*)d_in[2];
    const float* beta = (const float*)d_in[3];
    float* out = (float*)d_out;

    const int HW = in_sizes[1] / N_IMG;  // 65536

    float2* P = (float2*)((char*)d_ws + P_OFF);
    int* cnt = (int*)((char*)d_ws + CNT_OFF);

    // counts are accumulated with atomics -> must be zeroed every call
    hipMemsetAsync((char*)d_ws + CNT_OFF, 0, N_IMG * K_INS * sizeof(int), stream);

    count_kernel<<<dim3(32, N_IMG), 256, 0, stream>>>(ids, cnt, HW);
    stats_kernel<<<dim3(CCH, N_IMG, SPL), 256, 0, stream>>>(x, ids, P, HW);
    norm_kernel<<<dim3(CCH, N_IMG, SPL), 256, 0, stream>>>(x, ids, P, cnt, gamma, beta, out, HW);
}